// Round 18
// baseline (3622.195 us; speedup 1.0000x reference)
//
#include <hip/hip_runtime.h>

#define A_TOTAL 21760
#define NBATCH 8
#define FGC 20
#define NCAND 400
#define CAP 8192
#define POSTN 100
#define NBINS 1793
#define NBINS_PAD 1856
#define BIN_BASE15 30720u   // (0x3C000000 >> 15) : 0.0078125f bin lower bound

// ---------------------------------------------------------------------------
// XLA:CPU vectorized f32 exp (GenerateVF32Exp / Eigen pexp, Cephes form):
//   fx = floor(x*log2e + 0.5); two-step Cody-Waite; Horner; scale 2^fx.
// ---------------------------------------------------------------------------
__device__ __forceinline__ float np_expf(float x)
{
    float fx = __fadd_rn(__fmul_rn(x, 1.44269504088896341f), 0.5f);
    fx = floorf(fx);
    float xr = fmaf(fx, -0.693359375f, x);
    xr = fmaf(fx, 2.12194440e-4f, xr);
    float p = 1.9875691500E-4f;
    p = fmaf(p, xr, 1.3981999507E-3f);
    p = fmaf(p, xr, 8.3334519073E-3f);
    p = fmaf(p, xr, 4.1665795894E-2f);
    p = fmaf(p, xr, 1.6666665459E-1f);
    p = fmaf(p, xr, 5.0000001201E-1f);
    p = fmaf(p, __fmul_rn(xr, xr), xr);
    p = __fadd_rn(p, 1.0f);
    int qi = (int)fx;
    if (qi < -126) {
        p = __fmul_rn(p, __uint_as_float((unsigned)(qi + 253) << 23));
        return __fmul_rn(p, __uint_as_float(1u << 23));
    }
    return __fmul_rn(p, __uint_as_float((unsigned)(qi + 127) << 23));
}

// ---------------------------------------------------------------------------
// Fused cls+box 3x3 SAME conv, f32 sequential-FMA accumulation (c outer),
// LDS-tiled.  Conv realization proven selection-irrelevant (r2..r14).
//   cls_ws: float [B][A_total][21], box_ws: float [B][A_total][4]
// ---------------------------------------------------------------------------
template<int C, int HW, int TY>
__global__ __launch_bounds__(HW*TY)
void conv_head(const float* __restrict__ feat,
               const float* __restrict__ cw, const float* __restrict__ cb,
               const float* __restrict__ bw, const float* __restrict__ bb,
               float* __restrict__ cls_ws, float* __restrict__ box_ws,
               int anchor_off)
{
    constexpr int TX = HW;
    __shared__ float tile[TY+2][TX+2];
    const int tx = threadIdx.x, ty = threadIdx.y;
    const int og = blockIdx.x;          // 0..24 (21 cls groups, 4 box groups)
    const int y0 = blockIdx.y * TY;
    const int b  = blockIdx.z;
    const int tid = ty*TX + tx;
    const int nth = TX*TY;

    const bool is_cls = (og < 21);
    const int ocl0 = is_cls ? og*4 : og*4 - 84;
    const float* wb = is_cls ? cw : bw;

    float acc[4] = {0.f, 0.f, 0.f, 0.f};
    const float* fb = feat + (size_t)b * C * HW * HW;

    #pragma unroll 1
    for (int c = 0; c < C; ++c) {
        const float* fc = fb + (size_t)c * HW * HW;
        for (int t = tid; t < (TY+2)*(TX+2); t += nth) {
            int row = t / (TX+2), col = t % (TX+2);
            int gy = y0 + row - 1, gx = col - 1;
            float v = 0.f;
            if (gy >= 0 && gy < HW && (unsigned)gx < (unsigned)HW)
                v = fc[gy*HW + gx];
            tile[row][col] = v;
        }
        __syncthreads();
        float v00=tile[ty][tx],   v01=tile[ty][tx+1],   v02=tile[ty][tx+2];
        float v10=tile[ty+1][tx], v11=tile[ty+1][tx+1], v12=tile[ty+1][tx+2];
        float v20=tile[ty+2][tx], v21=tile[ty+2][tx+1], v22=tile[ty+2][tx+2];
        #pragma unroll
        for (int o = 0; o < 4; ++o) {
            const float* wp = wb + ((size_t)(ocl0+o)*C + c)*9;
            float t = acc[o];
            t = fmaf(v00, wp[0], t); t = fmaf(v01, wp[1], t); t = fmaf(v02, wp[2], t);
            t = fmaf(v10, wp[3], t); t = fmaf(v11, wp[4], t); t = fmaf(v12, wp[5], t);
            t = fmaf(v20, wp[6], t); t = fmaf(v21, wp[7], t); t = fmaf(v22, wp[8], t);
            acc[o] = t;
        }
        __syncthreads();
    }

    const int x = tx, y = y0 + ty;
    const int pos = y*HW + x;
    if (is_cls) {
        size_t base = ((size_t)b*A_TOTAL + anchor_off)*21 + (size_t)pos*84 + (size_t)og*4;
        #pragma unroll
        for (int o = 0; o < 4; ++o) cls_ws[base+o] = __fadd_rn(acc[o], cb[og*4+o]);
    } else {
        size_t base = ((size_t)b*A_TOTAL + anchor_off)*4 + (size_t)pos*16 + (size_t)ocl0;
        #pragma unroll
        for (int o = 0; o < 4; ++o) box_ws[base+o] = __fadd_rn(acc[o], bb[ocl0+o]);
    }
}

// XLA:CPU f32 softmax over trailing 21: max, Cephes exp, then the XLA
// masked-vector reduce: 8-wide accumulator over chunks {e0-7, e8-15,
// masked e16-20} (lanewise adds; masked lanes add exact 0), then reassoc
// shuffle fold 8->4->2->1.  a_i=(e_i+e_{i+8})+tail_i; b_i=a_i+a_{i+4};
// c_i=b_i+b_{i+2}; s=c_0+c_1.
__device__ __forceinline__ float np_softmax21(const float* lg, float* e)
{
    float l[21];
    #pragma unroll
    for (int i = 0; i < 21; ++i) l[i] = lg[i];
    float m = l[0];
    #pragma unroll
    for (int i = 1; i < 21; ++i) m = fmaxf(m, l[i]);
    #pragma unroll
    for (int i = 0; i < 21; ++i)
        e[i] = np_expf(__fsub_rn(l[i], m));
    float a0 = __fadd_rn(__fadd_rn(e[0], e[8]),  e[16]);
    float a1 = __fadd_rn(__fadd_rn(e[1], e[9]),  e[17]);
    float a2 = __fadd_rn(__fadd_rn(e[2], e[10]), e[18]);
    float a3 = __fadd_rn(__fadd_rn(e[3], e[11]), e[19]);
    float a4 = __fadd_rn(__fadd_rn(e[4], e[12]), e[20]);
    float a5 = __fadd_rn(e[5], e[13]);
    float a6 = __fadd_rn(e[6], e[14]);
    float a7 = __fadd_rn(e[7], e[15]);
    float b0 = __fadd_rn(a0, a4), b1 = __fadd_rn(a1, a5);
    float b2 = __fadd_rn(a2, a6), b3 = __fadd_rn(a3, a7);
    float c0 = __fadd_rn(b0, b2), c1 = __fadd_rn(b1, b3);
    return __fadd_rn(c0, c1);
}

// ---------------------------------------------------------------------------
// Per-anchor: softmax -> score histogram (rank-400 cutoff); f32 anchor gen +
// f32 bbox decode in reference op order.
// ---------------------------------------------------------------------------
__global__ __launch_bounds__(256)
void decode_kernel(const float* __restrict__ cls_ws, const float* __restrict__ boxd_ws,
                   float* __restrict__ bbox_ws, unsigned int* __restrict__ ghist)
{
    __shared__ unsigned int hist[NBINS_PAD];
    const int b = blockIdx.y;
    const int a = blockIdx.x*256 + threadIdx.x;    // 85*256 == 21760 exact
    for (int i = threadIdx.x; i < NBINS_PAD; i += 256) hist[i] = 0;
    __syncthreads();

    float e[21];
    float s = np_softmax21(cls_ws + ((size_t)b*A_TOTAL + a)*21, e);
    #pragma unroll
    for (int c = 0; c < FGC; ++c) {
        float p32 = __fdiv_rn(e[c+1], s);
        if (p32 > 0.01f) {
            unsigned int bin = (__float_as_uint(p32) >> 15) - BIN_BASE15;
            if (bin > NBINS-1) bin = NBINS-1;
            atomicAdd(&hist[bin], 1u);
        }
    }

    // anchor (cx,cy,w,h) in f32 per reference
    int lvl, idx, hwl; float stepf;
    if (a < 16384)      { lvl=0; idx=a;         hwl=64; stepf=8.f;  }
    else if (a < 20480) { lvl=1; idx=a-16384;   hwl=32; stepf=16.f; }
    else if (a < 21504) { lvl=2; idx=a-20480;   hwl=16; stepf=32.f; }
    else                { lvl=3; idx=a-21504;   hwl=8;  stepf=64.f; }
    const int d = idx & 3, p2 = idx >> 2;
    const int gx = p2 & (hwl-1), gy = p2 / hwl;
    const float axf = __fmul_rn(__fadd_rn((float)gx, 0.5f), stepf);
    const float ayf = __fmul_rn(__fadd_rn((float)gy, 0.5f), stepf);
    const double s0d[4] = {51.2, 102.4, 189.4, 276.4};
    const double s1d[4] = {102.4, 189.4, 276.4, 363.5};
    double s0 = s0d[lvl], wd, hd;
    if (d == 0)      { wd = s0; hd = s0; }
    else if (d == 1) { double t = sqrt(s0*s1d[lvl]); wd = t; hd = t; }
    else if (d == 2) { double sr = sqrt(2.0); wd = s0*sr; hd = s0/sr; }
    else             { double sr = sqrt(0.5); wd = s0*sr; hd = s0/sr; }
    const float awf = (float)wd, ahf = (float)hd;

    // f32 decode, reference op order: ((t*std)*aw)+ax ; ((exp*aw)*0.5)
    const float* bd = boxd_ws + ((size_t)b*A_TOTAL + a)*4;
    float t0=bd[0], t1=bd[1], t2=bd[2], t3=bd[3];
    float ox  = __fadd_rn(__fmul_rn(__fmul_rn(t0, 0.1f), awf), axf);
    float oy  = __fadd_rn(__fmul_rn(__fmul_rn(t1, 0.1f), ahf), ayf);
    float e2  = np_expf(__fmul_rn(t2, 0.2f));
    float e3  = np_expf(__fmul_rn(t3, 0.2f));
    float hw2 = __fmul_rn(__fmul_rn(e2, awf), 0.5f);
    float hh2 = __fmul_rn(__fmul_rn(e3, ahf), 0.5f);
    float* ob = bbox_ws + ((size_t)b*A_TOTAL + a)*4;
    ob[0]=__fsub_rn(ox,hw2); ob[1]=__fsub_rn(oy,hh2);
    ob[2]=__fadd_rn(ox,hw2); ob[3]=__fadd_rn(oy,hh2);

    __syncthreads();
    for (int i = threadIdx.x; i < NBINS_PAD; i += 256) {
        unsigned int h = hist[i];
        if (h) atomicAdd(&ghist[(size_t)b*NBINS_PAD + i], h);
    }
}

// Find the bin containing rank 400 from the top; cutoff = bin lower bound.
__global__ void cutoff_kernel(const unsigned int* __restrict__ ghist,
                              unsigned int* __restrict__ cutoff)
{
    const int b = blockIdx.x;
    if (threadIdx.x == 0) {
        const unsigned int* h = ghist + (size_t)b*NBINS_PAD;
        unsigned int cum = 0; int binlo = 0;
        for (int i = NBINS-1; i >= 0; --i) {
            cum += h[i];
            if (cum >= NCAND) { binlo = i; break; }
        }
        cutoff[b] = ((unsigned int)binlo + BIN_BASE15) << 15;
    }
}

// Compact candidates into 64-bit keys {hi = ~f32_score_bits, lo = row}.
// Ascending == score desc, row ASC among equal scores (stable argsort(-s)).
__global__ __launch_bounds__(256)
void compact_kernel(const float* __restrict__ cls_ws,
                    const unsigned int* __restrict__ cutoff,
                    unsigned int* __restrict__ cnt,
                    unsigned long long* __restrict__ keys)
{
    const int b = blockIdx.y;
    const int a = blockIdx.x*256 + threadIdx.x;
    float e[21];
    float s = np_softmax21(cls_ws + ((size_t)b*A_TOTAL + a)*21, e);
    const unsigned int cut = cutoff[b];
    #pragma unroll
    for (int c = 0; c < FGC; ++c) {
        float p32 = __fdiv_rn(e[c+1], s);
        if (p32 > 0.01f) {
            unsigned int bits = __float_as_uint(p32);
            if (bits >= cut) {
                unsigned int pos = atomicAdd(&cnt[b], 1u);
                if (pos < CAP)
                    keys[(size_t)b*CAP + pos] =
                        ((unsigned long long)(~bits) << 32) | (unsigned int)(c*A_TOTAL + a);
            }
        }
    }
}

// ---------------------------------------------------------------------------
// Per-batch: bitonic sort CAP 64-bit keys in 64KB LDS, top-400, NMS in f32
// (sequential-equivalent via suppression bitmasks), write top-100.
// Output: ids[8*100] | scores[8*100] | bboxes[8*100*4]  (f32)
// ---------------------------------------------------------------------------
__global__ __launch_bounds__(1024)
void sort_nms_kernel(const unsigned long long* __restrict__ keys,
                     const unsigned int* __restrict__ cnt,
                     const float* __restrict__ bbox_ws,
                     float* __restrict__ out)
{
    __shared__ unsigned long long sk[CAP];   // 64 KB
    const int b = blockIdx.x;
    const int tid = threadIdx.x;
    unsigned int nraw = cnt[b];
    const int n = (int)(nraw < (unsigned)CAP ? nraw : (unsigned)CAP);

    for (int i = tid; i < CAP; i += 1024)
        sk[i] = (i < n) ? keys[(size_t)b*CAP + i] : ~0ULL;
    __syncthreads();

    for (int k = 2; k <= CAP; k <<= 1) {
        for (int j = k >> 1; j > 0; j >>= 1) {
            for (int i = tid; i < CAP; i += 1024) {
                int ixj = i ^ j;
                if (ixj > i) {
                    unsigned long long va = sk[i], vb2 = sk[ixj];
                    bool dirUp = ((i & k) == 0);
                    if ((va > vb2) == dirUp) { sk[i] = vb2; sk[ixj] = va; }
                }
            }
            __syncthreads();
        }
    }

    // Scratch carved past the live sorted head (sk[0..399] = 3200 B < 4096).
    float* bx1 = (float*)(sk + 512);     // byte 4096
    float* by1 = bx1 + NCAND;
    float* bx2 = by1 + NCAND;
    float* by2 = bx2 + NCAND;
    float* bsc = by2 + NCAND;
    int*   bcl = (int*)(bsc + NCAND);
    int*   bva = bcl + NCAND;
    unsigned long long* sup   = (unsigned long long*)(bva + NCAND); // [400][7]
    unsigned long long* keepw = sup + NCAND*7;                      // [7]

    const int nc = n < NCAND ? n : NCAND;
    if (tid < NCAND) {
        bool valid = tid < nc;
        float x1v=0.f, y1v=0.f, x2v=0.f, y2v=0.f, scv=0.f; int cv=-1;
        if (valid) {
            unsigned long long key = sk[tid];
            unsigned int r = (unsigned int)(key & 0xFFFFFFFFull);
            unsigned int bits = ~(unsigned int)(key >> 32);
            scv = __uint_as_float(bits);
            cv = (int)(r / A_TOTAL);
            int aa = (int)(r - (unsigned)cv*A_TOTAL);
            const float* bp = bbox_ws + ((size_t)b*A_TOTAL + aa)*4;
            x1v=bp[0]; y1v=bp[1]; x2v=bp[2]; y2v=bp[3];
        }
        bx1[tid]=x1v; by1[tid]=y1v; bx2[tid]=x2v; by2[tid]=y2v;
        bsc[tid]=scv; bcl[tid]=cv; bva[tid]=valid?1:0;
    }
    __syncthreads();

    if (tid < 7) {
        unsigned long long kw = 0;
        for (int t2 = 0; t2 < 64; ++t2) {
            int i = tid*64 + t2;
            if (i < NCAND && bva[i]) kw |= (1ULL << t2);
        }
        keepw[tid] = kw;
    }

    // suppression matrix (f32 IoU, reference op order): sup[i][w] bit t -> j
    for (int u = tid; u < NCAND*7; u += 1024) {
        int i = u / 7, w = u % 7;
        float xi1=bx1[i], yi1=by1[i], xi2=bx2[i], yi2=by2[i];
        int ci = bcl[i];
        float ai = __fmul_rn(fmaxf(__fsub_rn(xi2,xi1),0.f),
                             fmaxf(__fsub_rn(yi2,yi1),0.f));
        unsigned long long mmask = 0;
        int jbase = w*64;
        for (int t2 = 0; t2 < 64; ++t2) {
            int j = jbase + t2;
            if (j < NCAND && j > i && bcl[j] == ci) {
                float iw = fmaxf(__fsub_rn(fminf(xi2, bx2[j]), fmaxf(xi1, bx1[j])), 0.f);
                float ih = fmaxf(__fsub_rn(fminf(yi2, by2[j]), fmaxf(yi1, by1[j])), 0.f);
                float inter = __fmul_rn(iw, ih);
                float aj = __fmul_rn(fmaxf(__fsub_rn(bx2[j],bx1[j]),0.f),
                                     fmaxf(__fsub_rn(by2[j],by1[j]),0.f));
                float den = __fadd_rn(__fsub_rn(__fadd_rn(ai, aj), inter), 1e-12f);
                float iou = __fdiv_rn(inter, den);
                if (iou > 0.45f) mmask |= (1ULL << t2);
            }
        }
        sup[i*7 + w] = mmask;
    }
    __syncthreads();

    if (tid == 0) {
        for (int i = 0; i < NCAND; ++i) {
            if ((keepw[i>>6] >> (i & 63)) & 1ULL) {
                #pragma unroll
                for (int w = 0; w < 7; ++w) keepw[w] &= ~sup[i*7 + w];
            }
        }
    }
    __syncthreads();

    // default fill -1
    for (int k2 = tid; k2 < POSTN; k2 += 1024) {
        out[b*POSTN + k2] = -1.f;
        out[NBATCH*POSTN + b*POSTN + k2] = -1.f;
        float* bo = out + 2*NBATCH*POSTN + ((size_t)(b*POSTN + k2))*4;
        bo[0]=bo[1]=bo[2]=bo[3]=-1.f;
    }
    __syncthreads();

    if (tid < NCAND) {
        int w = tid >> 6, bit = tid & 63;
        if ((keepw[w] >> bit) & 1ULL) {
            int rank = 0;
            for (int ww = 0; ww < w; ++ww) rank += __popcll(keepw[ww]);
            rank += __popcll(keepw[w] & (bit ? ((1ULL << bit) - 1) : 0ULL));
            if (rank < POSTN) {
                out[b*POSTN + rank] = (float)bcl[tid];
                out[NBATCH*POSTN + b*POSTN + rank] = bsc[tid];
                float* bo = out + 2*NBATCH*POSTN + ((size_t)(b*POSTN + rank))*4;
                bo[0]=bx1[tid]; bo[1]=by1[tid]; bo[2]=bx2[tid]; bo[3]=by2[tid];
            }
        }
    }
}

// ---------------------------------------------------------------------------
extern "C" void kernel_launch(void* const* d_in, const int* in_sizes, int n_in,
                              void* d_out, int out_size, void* d_ws, size_t ws_size,
                              hipStream_t stream) {
    const float* feat0 = (const float*)d_in[0];
    const float* feat1 = (const float*)d_in[1];
    const float* feat2 = (const float*)d_in[2];
    const float* feat3 = (const float*)d_in[3];
    const float* cw[4], *cb[4], *bw[4], *bb[4];
    for (int l = 0; l < 4; ++l) {
        cw[l] = (const float*)d_in[4 + 4*l + 0];
        cb[l] = (const float*)d_in[4 + 4*l + 1];
        bw[l] = (const float*)d_in[4 + 4*l + 2];
        bb[l] = (const float*)d_in[4 + 4*l + 3];
    }

    char* p = (char*)d_ws;
    float* cls_ws  = (float*)p; p += (size_t)NBATCH*A_TOTAL*21*4;  // 14.62 MB
    float* boxd_ws = (float*)p; p += (size_t)NBATCH*A_TOTAL*4*4;   //  2.79 MB
    float* bbox_ws = (float*)p; p += (size_t)NBATCH*A_TOTAL*4*4;   //  2.79 MB
    unsigned int* ghist = (unsigned int*)p; p += (size_t)NBATCH*NBINS_PAD*4; // 58 KB
    unsigned int* cntp  = (unsigned int*)p; p += 64;
    unsigned int* cutp  = (unsigned int*)p; p += 64;
    unsigned long long* keys = (unsigned long long*)p; p += (size_t)NBATCH*CAP*8; // 512 KB

    // zero hist + counters (contiguous)
    (void)hipMemsetAsync(ghist, 0, (size_t)NBATCH*NBINS_PAD*4 + 64, stream);

    conv_head<512,64,4 ><<<dim3(25,16,8), dim3(64,4),  0, stream>>>(feat0, cw[0],cb[0],bw[0],bb[0], cls_ws, boxd_ws, 0);
    conv_head<1024,32,8><<<dim3(25, 4,8), dim3(32,8),  0, stream>>>(feat1, cw[1],cb[1],bw[1],bb[1], cls_ws, boxd_ws, 16384);
    conv_head<512,16,16><<<dim3(25, 1,8), dim3(16,16), 0, stream>>>(feat2, cw[2],cb[2],bw[2],bb[2], cls_ws, boxd_ws, 20480);
    conv_head<256, 8,8 ><<<dim3(25, 1,8), dim3(8,8),   0, stream>>>(feat3, cw[3],cb[3],bw[3],bb[3], cls_ws, boxd_ws, 21504);

    decode_kernel<<<dim3(85,8), 256, 0, stream>>>(cls_ws, boxd_ws, bbox_ws, ghist);
    cutoff_kernel<<<8, 64, 0, stream>>>(ghist, cutp);
    compact_kernel<<<dim3(85,8), 256, 0, stream>>>(cls_ws, cutp, cntp, keys);
    sort_nms_kernel<<<8, 1024, 0, stream>>>(keys, cntp, bbox_ws, (float*)d_out);
}

// Round 19
// 2853.290 us; speedup vs baseline: 1.2695x; 1.2695x over previous
//
#include <hip/hip_runtime.h>

#define A_TOTAL 21760
#define NBATCH 8
#define FGC 20
#define NCAND 400
#define CAP 8192
#define POSTN 100
#define NBINS 1793
#define NBINS_PAD 1856
#define BIN_BASE15 30720u   // (0x3C000000 >> 15) : 0.0078125f bin lower bound

// ---------------------------------------------------------------------------
// XLA:CPU vectorized f32 exp (GenerateVF32Exp / Eigen pexp, Cephes form):
//   fx = floor(x*log2e + 0.5); two-step Cody-Waite; Horner; scale 2^fx.
// ---------------------------------------------------------------------------
__device__ __forceinline__ float np_expf(float x)
{
    float fx = __fadd_rn(__fmul_rn(x, 1.44269504088896341f), 0.5f);
    fx = floorf(fx);
    float xr = fmaf(fx, -0.693359375f, x);
    xr = fmaf(fx, 2.12194440e-4f, xr);
    float p = 1.9875691500E-4f;
    p = fmaf(p, xr, 1.3981999507E-3f);
    p = fmaf(p, xr, 8.3334519073E-3f);
    p = fmaf(p, xr, 4.1665795894E-2f);
    p = fmaf(p, xr, 1.6666665459E-1f);
    p = fmaf(p, xr, 5.0000001201E-1f);
    p = fmaf(p, __fmul_rn(xr, xr), xr);
    p = __fadd_rn(p, 1.0f);
    int qi = (int)fx;
    if (qi < -126) {
        p = __fmul_rn(p, __uint_as_float((unsigned)(qi + 253) << 23));
        return __fmul_rn(p, __uint_as_float(1u << 23));
    }
    return __fmul_rn(p, __uint_as_float((unsigned)(qi + 127) << 23));
}

// ---------------------------------------------------------------------------
// Fused cls+box 3x3 SAME conv.  Per-accumulator FMA chain BIT-IDENTICAL to
// the r18 passing kernel (c ascending, taps 0..8 row-major per channel);
// restructured for VALU efficiency: fill-slot descriptors hoisted out of the
// channel loop, 4 channels staged per barrier round (8x fewer barriers),
// walking wave-uniform weight pointers (scalar loads).
//   cls_ws: float [B][A_total][21], box_ws: float [B][A_total][4]
// ---------------------------------------------------------------------------
template<int C, int HW, int TY>
__global__ __launch_bounds__(HW*TY)
void conv_head(const float* __restrict__ feat,
               const float* __restrict__ cw, const float* __restrict__ cb,
               const float* __restrict__ bw, const float* __restrict__ bb,
               float* __restrict__ cls_ws, float* __restrict__ box_ws,
               int anchor_off)
{
    constexpr int TX = HW;
    constexpr int NTH = TX*TY;
    constexpr int NF = (TY+2)*(TX+2);
    constexpr int CHUNK = 4;
    constexpr int NSLOT = (CHUNK*NF + NTH - 1)/NTH;
    __shared__ float tile[CHUNK*NF];

    const int tx = threadIdx.x, ty = threadIdx.y;
    const int og = blockIdx.x;          // 0..24 (21 cls groups, 4 box groups)
    const int y0 = blockIdx.y * TY;
    const int b  = blockIdx.z;
    const int tid = ty*TX + tx;

    const bool is_cls = (og < 21);
    const int ocl0 = is_cls ? og*4 : og*4 - 84;
    const float* wb = is_cls ? cw : bw;
    const float* fb = feat + (size_t)b * C * HW * HW;

    // hoisted fill-slot descriptors (independent of channel)
    int  s_lds[NSLOT];    // flattened LDS offset (= ci*NF + r)
    int  s_goff[NSLOT];   // ci*HW*HW + gy*HW + gx (0 if invalid)
    bool s_ok[NSLOT];     // in-bounds (pad lanes write 0)
    bool s_act[NSLOT];    // slot exists
    #pragma unroll
    for (int s = 0; s < NSLOT; ++s) {
        int t = tid + s*NTH;
        bool act = (t < CHUNK*NF);
        int tc = act ? t : 0;
        int ci  = tc / NF;
        int r   = tc - ci*NF;
        int row = r / (TX+2);
        int col = r - row*(TX+2);
        int gy = y0 + row - 1, gx = col - 1;
        bool ok = act && ((unsigned)gy < (unsigned)HW) && ((unsigned)gx < (unsigned)HW);
        s_lds[s] = tc;
        s_goff[s] = ok ? (ci*HW*HW + gy*HW + gx) : 0;
        s_ok[s] = ok;
        s_act[s] = act;
    }

    float a0 = 0.f, a1 = 0.f, a2 = 0.f, a3 = 0.f;
    const int tbase = ty*(TX+2) + tx;   // tap-read base within one channel tile

    const float* w0p = wb + (size_t)(ocl0+0)*C*9;
    const float* w1p = wb + (size_t)(ocl0+1)*C*9;
    const float* w2p = wb + (size_t)(ocl0+2)*C*9;
    const float* w3p = wb + (size_t)(ocl0+3)*C*9;

    #pragma unroll 1
    for (int c0 = 0; c0 < C; c0 += CHUNK) {
        const float* fchunk = fb + (size_t)c0*HW*HW;
        #pragma unroll
        for (int s = 0; s < NSLOT; ++s) {
            if (s_act[s]) {
                float vv = 0.f;
                if (s_ok[s]) vv = fchunk[s_goff[s]];
                tile[s_lds[s]] = vv;
            }
        }
        __syncthreads();

        #pragma unroll
        for (int cc = 0; cc < CHUNK; ++cc) {
            const float* tp = tile + cc*NF + tbase;
            float v00=tp[0],        v01=tp[1],        v02=tp[2];
            float v10=tp[TX+2],     v11=tp[TX+3],     v12=tp[TX+4];
            float v20=tp[2*(TX+2)], v21=tp[2*(TX+2)+1], v22=tp[2*(TX+2)+2];
            const int wo = (c0+cc)*9;
            const float* q0 = w0p + wo; const float* q1 = w1p + wo;
            const float* q2 = w2p + wo; const float* q3 = w3p + wo;
            a0 = fmaf(v00,q0[0],a0); a0 = fmaf(v01,q0[1],a0); a0 = fmaf(v02,q0[2],a0);
            a0 = fmaf(v10,q0[3],a0); a0 = fmaf(v11,q0[4],a0); a0 = fmaf(v12,q0[5],a0);
            a0 = fmaf(v20,q0[6],a0); a0 = fmaf(v21,q0[7],a0); a0 = fmaf(v22,q0[8],a0);
            a1 = fmaf(v00,q1[0],a1); a1 = fmaf(v01,q1[1],a1); a1 = fmaf(v02,q1[2],a1);
            a1 = fmaf(v10,q1[3],a1); a1 = fmaf(v11,q1[4],a1); a1 = fmaf(v12,q1[5],a1);
            a1 = fmaf(v20,q1[6],a1); a1 = fmaf(v21,q1[7],a1); a1 = fmaf(v22,q1[8],a1);
            a2 = fmaf(v00,q2[0],a2); a2 = fmaf(v01,q2[1],a2); a2 = fmaf(v02,q2[2],a2);
            a2 = fmaf(v10,q2[3],a2); a2 = fmaf(v11,q2[4],a2); a2 = fmaf(v12,q2[5],a2);
            a2 = fmaf(v20,q2[6],a2); a2 = fmaf(v21,q2[7],a2); a2 = fmaf(v22,q2[8],a2);
            a3 = fmaf(v00,q3[0],a3); a3 = fmaf(v01,q3[1],a3); a3 = fmaf(v02,q3[2],a3);
            a3 = fmaf(v10,q3[3],a3); a3 = fmaf(v11,q3[4],a3); a3 = fmaf(v12,q3[5],a3);
            a3 = fmaf(v20,q3[6],a3); a3 = fmaf(v21,q3[7],a3); a3 = fmaf(v22,q3[8],a3);
        }
        __syncthreads();
    }

    const int pos = (y0 + ty)*HW + tx;
    float acc[4] = {a0, a1, a2, a3};
    if (is_cls) {
        size_t base = ((size_t)b*A_TOTAL + anchor_off)*21 + (size_t)pos*84 + (size_t)og*4;
        #pragma unroll
        for (int o = 0; o < 4; ++o) cls_ws[base+o] = __fadd_rn(acc[o], cb[og*4+o]);
    } else {
        size_t base = ((size_t)b*A_TOTAL + anchor_off)*4 + (size_t)pos*16 + (size_t)ocl0;
        #pragma unroll
        for (int o = 0; o < 4; ++o) box_ws[base+o] = __fadd_rn(acc[o], bb[ocl0+o]);
    }
}

// XLA:CPU f32 softmax over trailing 21: max, Cephes exp, then the XLA
// masked-vector reduce: 8-wide accumulator over chunks {e0-7, e8-15,
// masked e16-20} (lanewise adds; masked lanes add exact 0), then reassoc
// shuffle fold 8->4->2->1.  a_i=(e_i+e_{i+8})+tail_i; b_i=a_i+a_{i+4};
// c_i=b_i+b_{i+2}; s=c_0+c_1.
__device__ __forceinline__ float np_softmax21(const float* lg, float* e)
{
    float l[21];
    #pragma unroll
    for (int i = 0; i < 21; ++i) l[i] = lg[i];
    float m = l[0];
    #pragma unroll
    for (int i = 1; i < 21; ++i) m = fmaxf(m, l[i]);
    #pragma unroll
    for (int i = 0; i < 21; ++i)
        e[i] = np_expf(__fsub_rn(l[i], m));
    float a0 = __fadd_rn(__fadd_rn(e[0], e[8]),  e[16]);
    float a1 = __fadd_rn(__fadd_rn(e[1], e[9]),  e[17]);
    float a2 = __fadd_rn(__fadd_rn(e[2], e[10]), e[18]);
    float a3 = __fadd_rn(__fadd_rn(e[3], e[11]), e[19]);
    float a4 = __fadd_rn(__fadd_rn(e[4], e[12]), e[20]);
    float a5 = __fadd_rn(e[5], e[13]);
    float a6 = __fadd_rn(e[6], e[14]);
    float a7 = __fadd_rn(e[7], e[15]);
    float b0 = __fadd_rn(a0, a4), b1 = __fadd_rn(a1, a5);
    float b2 = __fadd_rn(a2, a6), b3 = __fadd_rn(a3, a7);
    float c0 = __fadd_rn(b0, b2), c1 = __fadd_rn(b1, b3);
    return __fadd_rn(c0, c1);
}

// ---------------------------------------------------------------------------
// Per-anchor: softmax -> score histogram (rank-400 cutoff); f32 anchor gen +
// f32 bbox decode in reference op order.
// ---------------------------------------------------------------------------
__global__ __launch_bounds__(256)
void decode_kernel(const float* __restrict__ cls_ws, const float* __restrict__ boxd_ws,
                   float* __restrict__ bbox_ws, unsigned int* __restrict__ ghist)
{
    __shared__ unsigned int hist[NBINS_PAD];
    const int b = blockIdx.y;
    const int a = blockIdx.x*256 + threadIdx.x;    // 85*256 == 21760 exact
    for (int i = threadIdx.x; i < NBINS_PAD; i += 256) hist[i] = 0;
    __syncthreads();

    float e[21];
    float s = np_softmax21(cls_ws + ((size_t)b*A_TOTAL + a)*21, e);
    #pragma unroll
    for (int c = 0; c < FGC; ++c) {
        float p32 = __fdiv_rn(e[c+1], s);
        if (p32 > 0.01f) {
            unsigned int bin = (__float_as_uint(p32) >> 15) - BIN_BASE15;
            if (bin > NBINS-1) bin = NBINS-1;
            atomicAdd(&hist[bin], 1u);
        }
    }

    // anchor (cx,cy,w,h) in f32 per reference
    int lvl, idx, hwl; float stepf;
    if (a < 16384)      { lvl=0; idx=a;         hwl=64; stepf=8.f;  }
    else if (a < 20480) { lvl=1; idx=a-16384;   hwl=32; stepf=16.f; }
    else if (a < 21504) { lvl=2; idx=a-20480;   hwl=16; stepf=32.f; }
    else                { lvl=3; idx=a-21504;   hwl=8;  stepf=64.f; }
    const int d = idx & 3, p2 = idx >> 2;
    const int gx = p2 & (hwl-1), gy = p2 / hwl;
    const float axf = __fmul_rn(__fadd_rn((float)gx, 0.5f), stepf);
    const float ayf = __fmul_rn(__fadd_rn((float)gy, 0.5f), stepf);
    const double s0d[4] = {51.2, 102.4, 189.4, 276.4};
    const double s1d[4] = {102.4, 189.4, 276.4, 363.5};
    double s0 = s0d[lvl], wd, hd;
    if (d == 0)      { wd = s0; hd = s0; }
    else if (d == 1) { double t = sqrt(s0*s1d[lvl]); wd = t; hd = t; }
    else if (d == 2) { double sr = sqrt(2.0); wd = s0*sr; hd = s0/sr; }
    else             { double sr = sqrt(0.5); wd = s0*sr; hd = s0/sr; }
    const float awf = (float)wd, ahf = (float)hd;

    // f32 decode, reference op order: ((t*std)*aw)+ax ; ((exp*aw)*0.5)
    const float* bd = boxd_ws + ((size_t)b*A_TOTAL + a)*4;
    float t0=bd[0], t1=bd[1], t2=bd[2], t3=bd[3];
    float ox  = __fadd_rn(__fmul_rn(__fmul_rn(t0, 0.1f), awf), axf);
    float oy  = __fadd_rn(__fmul_rn(__fmul_rn(t1, 0.1f), ahf), ayf);
    float e2  = np_expf(__fmul_rn(t2, 0.2f));
    float e3  = np_expf(__fmul_rn(t3, 0.2f));
    float hw2 = __fmul_rn(__fmul_rn(e2, awf), 0.5f);
    float hh2 = __fmul_rn(__fmul_rn(e3, ahf), 0.5f);
    float* ob = bbox_ws + ((size_t)b*A_TOTAL + a)*4;
    ob[0]=__fsub_rn(ox,hw2); ob[1]=__fsub_rn(oy,hh2);
    ob[2]=__fadd_rn(ox,hw2); ob[3]=__fadd_rn(oy,hh2);

    __syncthreads();
    for (int i = threadIdx.x; i < NBINS_PAD; i += 256) {
        unsigned int h = hist[i];
        if (h) atomicAdd(&ghist[(size_t)b*NBINS_PAD + i], h);
    }
}

// Find the bin containing rank 400 from the top; cutoff = bin lower bound.
__global__ void cutoff_kernel(const unsigned int* __restrict__ ghist,
                              unsigned int* __restrict__ cutoff)
{
    const int b = blockIdx.x;
    if (threadIdx.x == 0) {
        const unsigned int* h = ghist + (size_t)b*NBINS_PAD;
        unsigned int cum = 0; int binlo = 0;
        for (int i = NBINS-1; i >= 0; --i) {
            cum += h[i];
            if (cum >= NCAND) { binlo = i; break; }
        }
        cutoff[b] = ((unsigned int)binlo + BIN_BASE15) << 15;
    }
}

// Compact candidates into 64-bit keys {hi = ~f32_score_bits, lo = row}.
// Ascending == score desc, row ASC among equal scores (stable argsort(-s)).
__global__ __launch_bounds__(256)
void compact_kernel(const float* __restrict__ cls_ws,
                    const unsigned int* __restrict__ cutoff,
                    unsigned int* __restrict__ cnt,
                    unsigned long long* __restrict__ keys)
{
    const int b = blockIdx.y;
    const int a = blockIdx.x*256 + threadIdx.x;
    float e[21];
    float s = np_softmax21(cls_ws + ((size_t)b*A_TOTAL + a)*21, e);
    const unsigned int cut = cutoff[b];
    #pragma unroll
    for (int c = 0; c < FGC; ++c) {
        float p32 = __fdiv_rn(e[c+1], s);
        if (p32 > 0.01f) {
            unsigned int bits = __float_as_uint(p32);
            if (bits >= cut) {
                unsigned int pos = atomicAdd(&cnt[b], 1u);
                if (pos < CAP)
                    keys[(size_t)b*CAP + pos] =
                        ((unsigned long long)(~bits) << 32) | (unsigned int)(c*A_TOTAL + a);
            }
        }
    }
}

// ---------------------------------------------------------------------------
// Per-batch: bitonic sort CAP 64-bit keys in 64KB LDS, top-400, NMS in f32
// (sequential-equivalent via suppression bitmasks), write top-100.
// Output: ids[8*100] | scores[8*100] | bboxes[8*100*4]  (f32)
// ---------------------------------------------------------------------------
__global__ __launch_bounds__(1024)
void sort_nms_kernel(const unsigned long long* __restrict__ keys,
                     const unsigned int* __restrict__ cnt,
                     const float* __restrict__ bbox_ws,
                     float* __restrict__ out)
{
    __shared__ unsigned long long sk[CAP];   // 64 KB
    const int b = blockIdx.x;
    const int tid = threadIdx.x;
    unsigned int nraw = cnt[b];
    const int n = (int)(nraw < (unsigned)CAP ? nraw : (unsigned)CAP);

    for (int i = tid; i < CAP; i += 1024)
        sk[i] = (i < n) ? keys[(size_t)b*CAP + i] : ~0ULL;
    __syncthreads();

    for (int k = 2; k <= CAP; k <<= 1) {
        for (int j = k >> 1; j > 0; j >>= 1) {
            for (int i = tid; i < CAP; i += 1024) {
                int ixj = i ^ j;
                if (ixj > i) {
                    unsigned long long va = sk[i], vb2 = sk[ixj];
                    bool dirUp = ((i & k) == 0);
                    if ((va > vb2) == dirUp) { sk[i] = vb2; sk[ixj] = va; }
                }
            }
            __syncthreads();
        }
    }

    // Scratch carved past the live sorted head (sk[0..399] = 3200 B < 4096).
    float* bx1 = (float*)(sk + 512);     // byte 4096
    float* by1 = bx1 + NCAND;
    float* bx2 = by1 + NCAND;
    float* by2 = bx2 + NCAND;
    float* bsc = by2 + NCAND;
    int*   bcl = (int*)(bsc + NCAND);
    int*   bva = bcl + NCAND;
    unsigned long long* sup   = (unsigned long long*)(bva + NCAND); // [400][7]
    unsigned long long* keepw = sup + NCAND*7;                      // [7]

    const int nc = n < NCAND ? n : NCAND;
    if (tid < NCAND) {
        bool valid = tid < nc;
        float x1v=0.f, y1v=0.f, x2v=0.f, y2v=0.f, scv=0.f; int cv=-1;
        if (valid) {
            unsigned long long key = sk[tid];
            unsigned int r = (unsigned int)(key & 0xFFFFFFFFull);
            unsigned int bits = ~(unsigned int)(key >> 32);
            scv = __uint_as_float(bits);
            cv = (int)(r / A_TOTAL);
            int aa = (int)(r - (unsigned)cv*A_TOTAL);
            const float* bp = bbox_ws + ((size_t)b*A_TOTAL + aa)*4;
            x1v=bp[0]; y1v=bp[1]; x2v=bp[2]; y2v=bp[3];
        }
        bx1[tid]=x1v; by1[tid]=y1v; bx2[tid]=x2v; by2[tid]=y2v;
        bsc[tid]=scv; bcl[tid]=cv; bva[tid]=valid?1:0;
    }
    __syncthreads();

    if (tid < 7) {
        unsigned long long kw = 0;
        for (int t2 = 0; t2 < 64; ++t2) {
            int i = tid*64 + t2;
            if (i < NCAND && bva[i]) kw |= (1ULL << t2);
        }
        keepw[tid] = kw;
    }

    // suppression matrix (f32 IoU, reference op order): sup[i][w] bit t -> j
    for (int u = tid; u < NCAND*7; u += 1024) {
        int i = u / 7, w = u % 7;
        float xi1=bx1[i], yi1=by1[i], xi2=bx2[i], yi2=by2[i];
        int ci = bcl[i];
        float ai = __fmul_rn(fmaxf(__fsub_rn(xi2,xi1),0.f),
                             fmaxf(__fsub_rn(yi2,yi1),0.f));
        unsigned long long mmask = 0;
        int jbase = w*64;
        for (int t2 = 0; t2 < 64; ++t2) {
            int j = jbase + t2;
            if (j < NCAND && j > i && bcl[j] == ci) {
                float iw = fmaxf(__fsub_rn(fminf(xi2, bx2[j]), fmaxf(xi1, bx1[j])), 0.f);
                float ih = fmaxf(__fsub_rn(fminf(yi2, by2[j]), fmaxf(yi1, by1[j])), 0.f);
                float inter = __fmul_rn(iw, ih);
                float aj = __fmul_rn(fmaxf(__fsub_rn(bx2[j],bx1[j]),0.f),
                                     fmaxf(__fsub_rn(by2[j],by1[j]),0.f));
                float den = __fadd_rn(__fsub_rn(__fadd_rn(ai, aj), inter), 1e-12f);
                float iou = __fdiv_rn(inter, den);
                if (iou > 0.45f) mmask |= (1ULL << t2);
            }
        }
        sup[i*7 + w] = mmask;
    }
    __syncthreads();

    if (tid == 0) {
        for (int i = 0; i < NCAND; ++i) {
            if ((keepw[i>>6] >> (i & 63)) & 1ULL) {
                #pragma unroll
                for (int w = 0; w < 7; ++w) keepw[w] &= ~sup[i*7 + w];
            }
        }
    }
    __syncthreads();

    // default fill -1
    for (int k2 = tid; k2 < POSTN; k2 += 1024) {
        out[b*POSTN + k2] = -1.f;
        out[NBATCH*POSTN + b*POSTN + k2] = -1.f;
        float* bo = out + 2*NBATCH*POSTN + ((size_t)(b*POSTN + k2))*4;
        bo[0]=bo[1]=bo[2]=bo[3]=-1.f;
    }
    __syncthreads();

    if (tid < NCAND) {
        int w = tid >> 6, bit = tid & 63;
        if ((keepw[w] >> bit) & 1ULL) {
            int rank = 0;
            for (int ww = 0; ww < w; ++ww) rank += __popcll(keepw[ww]);
            rank += __popcll(keepw[w] & (bit ? ((1ULL << bit) - 1) : 0ULL));
            if (rank < POSTN) {
                out[b*POSTN + rank] = (float)bcl[tid];
                out[NBATCH*POSTN + b*POSTN + rank] = bsc[tid];
                float* bo = out + 2*NBATCH*POSTN + ((size_t)(b*POSTN + rank))*4;
                bo[0]=bx1[tid]; bo[1]=by1[tid]; bo[2]=bx2[tid]; bo[3]=by2[tid];
            }
        }
    }
}

// ---------------------------------------------------------------------------
extern "C" void kernel_launch(void* const* d_in, const int* in_sizes, int n_in,
                              void* d_out, int out_size, void* d_ws, size_t ws_size,
                              hipStream_t stream) {
    const float* feat0 = (const float*)d_in[0];
    const float* feat1 = (const float*)d_in[1];
    const float* feat2 = (const float*)d_in[2];
    const float* feat3 = (const float*)d_in[3];
    const float* cw[4], *cb[4], *bw[4], *bb[4];
    for (int l = 0; l < 4; ++l) {
        cw[l] = (const float*)d_in[4 + 4*l + 0];
        cb[l] = (const float*)d_in[4 + 4*l + 1];
        bw[l] = (const float*)d_in[4 + 4*l + 2];
        bb[l] = (const float*)d_in[4 + 4*l + 3];
    }

    char* p = (char*)d_ws;
    float* cls_ws  = (float*)p; p += (size_t)NBATCH*A_TOTAL*21*4;  // 14.62 MB
    float* boxd_ws = (float*)p; p += (size_t)NBATCH*A_TOTAL*4*4;   //  2.79 MB
    float* bbox_ws = (float*)p; p += (size_t)NBATCH*A_TOTAL*4*4;   //  2.79 MB
    unsigned int* ghist = (unsigned int*)p; p += (size_t)NBATCH*NBINS_PAD*4; // 58 KB
    unsigned int* cntp  = (unsigned int*)p; p += 64;
    unsigned int* cutp  = (unsigned int*)p; p += 64;
    unsigned long long* keys = (unsigned long long*)p; p += (size_t)NBATCH*CAP*8; // 512 KB

    // zero hist + counters (contiguous)
    (void)hipMemsetAsync(ghist, 0, (size_t)NBATCH*NBINS_PAD*4 + 64, stream);

    conv_head<512,64,4 ><<<dim3(25,16,8), dim3(64,4),  0, stream>>>(feat0, cw[0],cb[0],bw[0],bb[0], cls_ws, boxd_ws, 0);
    conv_head<1024,32,8><<<dim3(25, 4,8), dim3(32,8),  0, stream>>>(feat1, cw[1],cb[1],bw[1],bb[1], cls_ws, boxd_ws, 16384);
    conv_head<512,16,16><<<dim3(25, 1,8), dim3(16,16), 0, stream>>>(feat2, cw[2],cb[2],bw[2],bb[2], cls_ws, boxd_ws, 20480);
    conv_head<256, 8,8 ><<<dim3(25, 1,8), dim3(8,8),   0, stream>>>(feat3, cw[3],cb[3],bw[3],bb[3], cls_ws, boxd_ws, 21504);

    decode_kernel<<<dim3(85,8), 256, 0, stream>>>(cls_ws, boxd_ws, bbox_ws, ghist);
    cutoff_kernel<<<8, 64, 0, stream>>>(ghist, cutp);
    compact_kernel<<<dim3(85,8), 256, 0, stream>>>(cls_ws, cutp, cntp, keys);
    sort_nms_kernel<<<8, 1024, 0, stream>>>(keys, cntp, bbox_ws, (float*)d_out);
}